// Round 4
// baseline (243.696 us; speedup 1.0000x reference)
//
#include <hip/hip_runtime.h>
#include <math.h>

#define NPTS   4096   // points per set (n == m)
#define NPROJ  2000   // projections
#define NB     256    // threads per block
#define NMERGE 8192   // n + m
#define VPT    32     // values per thread (in registers)

// XOR-rotate swizzle: element-within-chunk rotated by chunk index (chunk = i>>5).
__device__ __forceinline__ int sw(int i) {
    return (i & ~31) | ((i + (i >> 5)) & 31);
}

// Bitonic local merge of 32 in-register elements, steps j=16..1, uniform direction.
__device__ __forceinline__ void local_merge(float v[VPT], bool asc) {
    #pragma unroll
    for (int j = 16; j >= 1; j >>= 1) {
        #pragma unroll
        for (int e = 0; e < VPT; ++e) {
            if ((e & j) == 0) {
                float a = v[e], b = v[e | j];
                float mn = fminf(a, b), mx = fmaxf(a, b);
                v[e]     = asc ? mn : mx;
                v[e | j] = asc ? mx : mn;
            }
        }
    }
}

// Occupancy/register history on this toolchain (empirical):
//   __launch_bounds__(256, W) caps allocator at ~256/W VGPRs AND caps runtime
//   residency at ~W blocks/CU (observed: W=4 -> 64 VGPR + spills + 40% occ;
//   W=5 -> 48 VGPR + 3x spill traffic; W=2 -> 88 VGPR, no spill, but 21% occ).
//   The single-value hint acts as min=max. Fix: explicit waves_per_eu range —
//   min=2 keeps the no-spill register budget, max=8 lets HW run 4-5 blocks/CU
//   (VGPR 88 -> 5 waves/SIMD; LDS 32 KiB -> 5 blocks/CU).
__global__ __launch_bounds__(NB) __attribute__((amdgpu_waves_per_eu(2, 8)))
void swd_kernel(
    const float* __restrict__ Xs, const float* __restrict__ Xt,
    const float* __restrict__ Us, float* __restrict__ out)
{
    // keys: sorted u || sorted v (swizzled addressing). Exactly 32 KiB -> 5 blocks/CU.
    // After the merge-path phase keys is dead; its head is reused for reductions:
    //   ired = (int*)keys   [0..7]   : block min/max of level c
    //   red  = keys + 8     [8..67]  : bisection partials (<=13 iters * 4) + final 4
    __shared__ float keys[NMERGE];

    const int tid  = threadIdx.x;
    const int arr  = tid >> 7;       // 0 = Xs chunk-owner, 1 = Xt
    const int c    = tid & 127;      // chunk index within this array (32 elems/chunk)
    const int lane = tid & 63;
    const int wid  = tid >> 6;
    const int p    = blockIdx.x;

    const float u00 = Us[p*6+0], u01 = Us[p*6+1];
    const float u10 = Us[p*6+2], u11 = Us[p*6+3];
    const float u20 = Us[p*6+4], u21 = Us[p*6+5];

    const float pi_f   = 3.14159265358979323846f;
    const float inv2pi = 0.15915494309189535f;

    const float* __restrict__ X = arr ? Xt : Xs;

    // ---- angles into registers (atan2 is scale-invariant; F.normalize skipped) ----
    float v[VPT];
    {
        const float4* X4 = (const float4*)(X + c * (VPT * 3));  // 96 floats, 16B aligned
        #pragma unroll
        for (int t = 0; t < 8; ++t) {
            float4 q0 = X4[t*3+0], q1 = X4[t*3+1], q2 = X4[t*3+2];
            #define ANG(x,y,z) ((atan2f(-((x)*u01+(y)*u11+(z)*u21), \
                                        -((x)*u00+(y)*u10+(z)*u20)) + pi_f) * inv2pi)
            v[t*4+0] = ANG(q0.x, q0.y, q0.z);
            v[t*4+1] = ANG(q0.w, q1.x, q1.y);
            v[t*4+2] = ANG(q1.z, q1.w, q2.x);
            v[t*4+3] = ANG(q2.y, q2.z, q2.w);
            #undef ANG
        }
    }

    // ---- phases k=2..16: intra-thread, compile-time directions ----
    #pragma unroll
    for (int k = 2; k <= 16; k <<= 1) {
        #pragma unroll
        for (int j = k >> 1; j >= 1; j >>= 1) {
            #pragma unroll
            for (int e = 0; e < VPT; ++e) {
                if ((e & j) == 0) {
                    bool asc = ((e & k) == 0);
                    float a = v[e], b = v[e | j];
                    float mn = fminf(a, b), mx = fmaxf(a, b);
                    v[e]     = asc ? mn : mx;
                    v[e | j] = asc ? mx : mn;
                }
            }
        }
    }

    // ---- phase k=32: fully local, direction uniform per thread ----
    local_merge(v, (c & 1) == 0);

    // ---- phases k=64..2048: within-wave shfl_xor exchanges + local merge ----
    #pragma unroll
    for (int k = 64; k <= 2048; k <<= 1) {
        bool asc = ((c & (k >> 5)) == 0);
        #pragma unroll
        for (int d = k >> 6; d >= 1; d >>= 1) {     // j = k/2 .. 32
            bool keepmin = (((c & d) == 0) == asc);
            #pragma unroll
            for (int e = 0; e < VPT; ++e) {
                float o = __shfl_xor(v[e], d, 64);
                v[e] = keepmin ? fminf(v[e], o) : fmaxf(v[e], o);
            }
        }
        local_merge(v, asc);
    }

    // ---- phase k=4096 (full ascending merge) ----
    // j=2048 crosses waves (chunk xor 64): one LDS round-trip.
    #pragma unroll
    for (int e = 0; e < VPT; ++e) keys[sw(tid * VPT + e)] = v[e];
    __syncthreads();
    {
        const int pbase = (tid ^ 64) * VPT;
        const bool keepmin = (c & 64) == 0;          // asc = true
        #pragma unroll
        for (int e = 0; e < VPT; ++e) {
            float o = keys[sw(pbase + e)];
            v[e] = keepmin ? fminf(v[e], o) : fmaxf(v[e], o);
        }
    }
    __syncthreads();   // all partner reads complete before keys is overwritten
    #pragma unroll
    for (int d = 32; d >= 1; d >>= 1) {              // j = 1024 .. 32
        bool keepmin = ((c & d) == 0);
        #pragma unroll
        for (int e = 0; e < VPT; ++e) {
            float o = __shfl_xor(v[e], d, 64);
            v[e] = keepmin ? fminf(v[e], o) : fmaxf(v[e], o);
        }
    }
    local_merge(v, true);

    // store sorted arrays for the merge
    #pragma unroll
    for (int e = 0; e < VPT; ++e) keys[sw(tid * VPT + e)] = v[e];
    __syncthreads();

    // ---- merge-path merge; keep (delta, c-offset) per element in registers ----
    // Level after merged element = (#u taken) - (#v taken); cdf value = c/4096 exact.
    // delta goes into v[s]; c stored as int8 offset from c_init, packed 4/VGPR.
    int c_init;
    int offmin = 64, offmax = -64;                   // per-thread range of c offsets
    unsigned int c8[8] = {0,0,0,0,0,0,0,0};
    {
        const int d0 = tid * VPT;
        int lo = d0 > NPTS ? d0 - NPTS : 0;
        int hi = d0 < NPTS ? d0 : NPTS;
        while (lo < hi) {                     // ties: u first (stable argsort)
            int mid = (lo + hi) >> 1;
            if (keys[sw(mid)] <= keys[sw(NPTS + (d0 - 1 - mid))]) lo = mid + 1; else hi = mid;
        }
        int i = lo, j = d0 - lo;
        c_init = i - j;
        const float FMAXV = 3.402823466e+38f;
        float cu = (i < NPTS) ? keys[sw(i)] : FMAXV;
        float cv = (j < NPTS) ? keys[sw(NPTS + j)] : FMAXV;
        #pragma unroll
        for (int s = 0; s < VPT; ++s) {
            float cur;
            if (cu <= cv) { cur = cu; ++i; cu = (i < NPTS) ? keys[sw(i)] : FMAXV; }
            else          { cur = cv; ++j; cv = (j < NPTS) ? keys[sw(NPTS + j)] : FMAXV; }
            float nxt = fminf(cu, cv);
            if (nxt == FMAXV) nxt = 1.0f;     // vals_pad appends 1.0
            v[s] = nxt - cur;                 // delta (>= 0)
            int off = (i - j) - c_init;       // in [-32, 32]
            offmin = min(offmin, off);
            offmax = max(offmax, off);
            c8[s >> 2] |= ((unsigned int)(off & 0xff)) << ((s & 3) * 8);
        }
    }

    __syncthreads();   // keys reads done everywhere; safe to reuse keys as scratch
    int*   ired = (int*)keys;       // keys[0..7]
    float* red  = keys + 8;         // keys[8..67]

    // ---- block min/max of level c: narrows the bisection to the attained range ----
    int cmn = c_init + offmin, cmx = c_init + offmax;
    #pragma unroll
    for (int o = 32; o >= 1; o >>= 1) {
        cmn = min(cmn, __shfl_xor(cmn, o, 64));
        cmx = max(cmx, __shfl_xor(cmx, o, 64));
    }
    if (lane == 0) { ired[wid] = cmn; ired[4 + wid] = cmx; }
    __syncthreads();
    cmn = min(min(ired[0], ired[1]), min(ired[2], ired[3]));
    cmx = max(max(ired[4], ired[5]), max(ired[6], ired[7]));

    // ---- level median c* via integer bisection (no histogram, no atomics) ----
    // c* = smallest c with W(<= c) >= 0.5, W = sum of deltas at levels <= c.
    // Invariant: W(<= lo) < 0.5 <= W(<= hi).
    int lo_c = cmn - 1, hi_c = cmx;
    int it = 0;
    #pragma unroll 1
    while (hi_c - lo_c > 1) {
        const int mid = (lo_c + hi_c) >> 1;   // uniform across block
        const int thr = mid - c_init;
        float s_loc = 0.0f;
        #pragma unroll
        for (int s = 0; s < VPT; ++s) {
            int off = (int)(c8[s >> 2] << ((3 - (s & 3)) * 8)) >> 24;  // sign-extended byte
            s_loc += (off <= thr) ? v[s] : 0.0f;
        }
        #pragma unroll
        for (int o = 32; o >= 1; o >>= 1) s_loc += __shfl_down(s_loc, o, 64);
        if (lane == 0) red[it * 4 + wid] = s_loc;
        __syncthreads();
        float S = red[it*4+0] + red[it*4+1] + red[it*4+2] + red[it*4+3];
        if (S >= 0.5f) hi_c = mid; else lo_c = mid;
        ++it;
    }
    const int cstar = hi_c;

    // ---- w1 = (1/4096) * sum delta * |c - c*| (register pass + one reduction) ----
    float part = 0.0f;
    {
        const int thr = cstar - c_init;
        #pragma unroll
        for (int s = 0; s < VPT; ++s) {
            int off = (int)(c8[s >> 2] << ((3 - (s & 3)) * 8)) >> 24;
            part += v[s] * fabsf((float)(off - thr));
        }
    }
    #pragma unroll
    for (int o = 32; o >= 1; o >>= 1) part += __shfl_down(part, o, 64);
    if (lane == 0) red[56 + wid] = part;
    __syncthreads();
    if (tid == 0) {
        float w1 = (red[56] + red[57] + red[58] + red[59]) * (1.0f / 4096.0f);
        atomicAdd(out, w1 * (1.0f / (float)NPROJ));
    }
}

extern "C" void kernel_launch(void* const* d_in, const int* in_sizes, int n_in,
                              void* d_out, int out_size, void* d_ws, size_t ws_size,
                              hipStream_t stream) {
    const float* Xs = (const float*)d_in[0];
    const float* Xt = (const float*)d_in[1];
    const float* Us = (const float*)d_in[2];
    float* out = (float*)d_out;

    hipMemsetAsync(out, 0, sizeof(float), stream);
    swd_kernel<<<NPROJ, NB, 0, stream>>>(Xs, Xt, Us, out);
}

// Round 5
// 230.119 us; speedup vs baseline: 1.0590x; 1.0590x over previous
//
#include <hip/hip_runtime.h>
#include <math.h>

#define NPTS   4096   // points per set (n == m)
#define NPROJ  2000   // projections
#define NB     512    // threads per block (8 waves)
#define NMERGE 8192   // n + m
#define VPT    16     // values per thread (in registers)

// XOR-rotate swizzle: element-within-chunk rotated by chunk index (chunk = i>>5).
__device__ __forceinline__ int sw(int i) {
    return (i & ~31) | ((i + (i >> 5)) & 31);
}

// Bitonic local merge of 16 in-register elements, steps j=8..1, uniform direction.
__device__ __forceinline__ void local_merge(float v[VPT], bool asc) {
    #pragma unroll
    for (int j = 8; j >= 1; j >>= 1) {
        #pragma unroll
        for (int e = 0; e < VPT; ++e) {
            if ((e & j) == 0) {
                float a = v[e], b = v[e | j];
                float mn = fminf(a, b), mx = fmaxf(a, b);
                v[e]     = asc ? mn : mx;
                v[e | j] = asc ? mx : mn;
            }
        }
    }
}

// NB=512/VPT=16: same total work, 8 waves/block. History: 256-thread/VPT=32
// variants were pinned at ~2 blocks/CU (6.7 waves) by an occupancy cap we
// could not lift via launch hints without VGPR spills (R1: budget 48 -> 3x
// HBM spill traffic; R3/R4: 88 VGPR no-spill but 21% occupancy). Halving
// per-thread state (~50 VGPR live) lets the default allocator stay <=64
// VGPRs with no hint, and 8-wave blocks give >=16 waves/CU even at the
// 2-block cap. No second launch_bounds arg: every explicit hint regressed.
__global__ __launch_bounds__(NB) void swd_kernel(
    const float* __restrict__ Xs, const float* __restrict__ Xt,
    const float* __restrict__ Us, float* __restrict__ out)
{
    // keys: sorted u || sorted v (swizzled addressing). Exactly 32 KiB.
    // After the merge-path phase keys is dead; its head is reused:
    //   ired = (int*)keys  [0..15]  : block min/max of level c (8 waves)
    //   red  = keys + 16            : bisection partials (<=15 iters * 8) + final 8
    __shared__ float keys[NMERGE];

    const int tid  = threadIdx.x;
    const int arr  = tid >> 8;       // 0 = Xs half, 1 = Xt half
    const int c    = tid & 255;      // chunk index within this array (16 elems/chunk)
    const int lane = tid & 63;
    const int wid  = tid >> 6;       // 0..7
    const int p    = blockIdx.x;

    const float u00 = Us[p*6+0], u01 = Us[p*6+1];
    const float u10 = Us[p*6+2], u11 = Us[p*6+3];
    const float u20 = Us[p*6+4], u21 = Us[p*6+5];

    const float pi_f   = 3.14159265358979323846f;
    const float inv2pi = 0.15915494309189535f;

    const float* __restrict__ X = arr ? Xt : Xs;

    // ---- angles into registers (atan2 is scale-invariant; F.normalize skipped) ----
    float v[VPT];
    {
        const float4* X4 = (const float4*)(X + c * (VPT * 3));  // 48 floats, 16B aligned
        #pragma unroll
        for (int t = 0; t < 4; ++t) {
            float4 q0 = X4[t*3+0], q1 = X4[t*3+1], q2 = X4[t*3+2];
            #define ANG(x,y,z) ((atan2f(-((x)*u01+(y)*u11+(z)*u21), \
                                        -((x)*u00+(y)*u10+(z)*u20)) + pi_f) * inv2pi)
            v[t*4+0] = ANG(q0.x, q0.y, q0.z);
            v[t*4+1] = ANG(q0.w, q1.x, q1.y);
            v[t*4+2] = ANG(q1.z, q1.w, q2.x);
            v[t*4+3] = ANG(q2.y, q2.z, q2.w);
            #undef ANG
        }
    }

    // ---- phases k=2..8: intra-thread, compile-time directions ----
    #pragma unroll
    for (int k = 2; k <= 8; k <<= 1) {
        #pragma unroll
        for (int j = k >> 1; j >= 1; j >>= 1) {
            #pragma unroll
            for (int e = 0; e < VPT; ++e) {
                if ((e & j) == 0) {
                    bool asc = ((e & k) == 0);
                    float a = v[e], b = v[e | j];
                    float mn = fminf(a, b), mx = fmaxf(a, b);
                    v[e]     = asc ? mn : mx;
                    v[e | j] = asc ? mx : mn;
                }
            }
        }
    }

    // ---- phase k=16: fully local, direction uniform per thread ----
    local_merge(v, (c & 1) == 0);

    // ---- phases k=32..1024: within-wave shfl_xor exchanges + local merge ----
    // global elem idx g = c*16 + e; direction asc = ((g & k)==0) = ((c & (k>>4))==0)
    #pragma unroll
    for (int k = 32; k <= 1024; k <<= 1) {
        bool asc = ((c & (k >> 4)) == 0);
        #pragma unroll
        for (int d = k >> 5; d >= 1; d >>= 1) {     // j = k/2 .. 16
            bool keepmin = (((c & d) == 0) == asc);
            #pragma unroll
            for (int e = 0; e < VPT; ++e) {
                float o = __shfl_xor(v[e], d, 64);
                v[e] = keepmin ? fminf(v[e], o) : fmaxf(v[e], o);
            }
        }
        local_merge(v, asc);
    }

    // LDS cross-wave exchange: write all, sync, read partner's 16, minmax, sync.
    #define LDS_XCHG(PXOR, KEEPMIN_EXPR)                                   \
    {                                                                      \
        _Pragma("unroll")                                                  \
        for (int e = 0; e < VPT; ++e) keys[sw(tid * VPT + e)] = v[e];      \
        __syncthreads();                                                   \
        const int pbase = (tid ^ (PXOR)) * VPT;                            \
        const bool keepmin = (KEEPMIN_EXPR);                               \
        _Pragma("unroll")                                                  \
        for (int e = 0; e < VPT; ++e) {                                    \
            float o = keys[sw(pbase + e)];                                 \
            v[e] = keepmin ? fminf(v[e], o) : fmaxf(v[e], o);              \
        }                                                                  \
        __syncthreads();                                                   \
    }

    // ---- phase k=2048: j=1024 crosses waves (c^64), then shfl + local ----
    {
        bool asc = ((c & 128) == 0);
        LDS_XCHG(64, ((c & 64) == 0) == asc);
        #pragma unroll
        for (int d = 32; d >= 1; d >>= 1) {          // j = 512 .. 16
            bool keepmin = (((c & d) == 0) == asc);
            #pragma unroll
            for (int e = 0; e < VPT; ++e) {
                float o = __shfl_xor(v[e], d, 64);
                v[e] = keepmin ? fminf(v[e], o) : fmaxf(v[e], o);
            }
        }
        local_merge(v, asc);
    }

    // ---- phase k=4096 (full ascending merge): j=2048 (c^128), j=1024 (c^64) ----
    LDS_XCHG(128, (c & 128) == 0);
    LDS_XCHG(64,  (c & 64) == 0);
    #pragma unroll
    for (int d = 32; d >= 1; d >>= 1) {              // j = 512 .. 16
        bool keepmin = ((c & d) == 0);
        #pragma unroll
        for (int e = 0; e < VPT; ++e) {
            float o = __shfl_xor(v[e], d, 64);
            v[e] = keepmin ? fminf(v[e], o) : fmaxf(v[e], o);
        }
    }
    local_merge(v, true);
    #undef LDS_XCHG

    // store sorted arrays for the merge
    #pragma unroll
    for (int e = 0; e < VPT; ++e) keys[sw(tid * VPT + e)] = v[e];
    __syncthreads();

    // ---- merge-path merge; keep (delta, c-offset) per element in registers ----
    // Level after merged element = (#u taken) - (#v taken); cdf value = c/4096 exact.
    // delta goes into v[s]; c stored as int8 offset from c_init, packed 4/VGPR.
    int c_init;
    int offmin = 32, offmax = -32;                   // per-thread range of c offsets
    unsigned int c8[4] = {0,0,0,0};
    {
        const int d0 = tid * VPT;
        int lo = d0 > NPTS ? d0 - NPTS : 0;
        int hi = d0 < NPTS ? d0 : NPTS;
        while (lo < hi) {                     // ties: u first (stable argsort)
            int mid = (lo + hi) >> 1;
            if (keys[sw(mid)] <= keys[sw(NPTS + (d0 - 1 - mid))]) lo = mid + 1; else hi = mid;
        }
        int i = lo, j = d0 - lo;
        c_init = i - j;
        const float FMAXV = 3.402823466e+38f;
        float cu = (i < NPTS) ? keys[sw(i)] : FMAXV;
        float cv = (j < NPTS) ? keys[sw(NPTS + j)] : FMAXV;
        #pragma unroll
        for (int s = 0; s < VPT; ++s) {
            float cur;
            if (cu <= cv) { cur = cu; ++i; cu = (i < NPTS) ? keys[sw(i)] : FMAXV; }
            else          { cur = cv; ++j; cv = (j < NPTS) ? keys[sw(NPTS + j)] : FMAXV; }
            float nxt = fminf(cu, cv);
            if (nxt == FMAXV) nxt = 1.0f;     // vals_pad appends 1.0
            v[s] = nxt - cur;                 // delta (>= 0)
            int off = (i - j) - c_init;       // in [-16, 16]
            offmin = min(offmin, off);
            offmax = max(offmax, off);
            c8[s >> 2] |= ((unsigned int)(off & 0xff)) << ((s & 3) * 8);
        }
    }

    __syncthreads();   // keys reads done everywhere; safe to reuse keys as scratch
    int*   ired = (int*)keys;       // keys[0..15]
    float* red  = keys + 16;        // keys[16..]

    // ---- block min/max of level c: narrows the bisection to the attained range ----
    int cmn = c_init + offmin, cmx = c_init + offmax;
    #pragma unroll
    for (int o = 32; o >= 1; o >>= 1) {
        cmn = min(cmn, __shfl_xor(cmn, o, 64));
        cmx = max(cmx, __shfl_xor(cmx, o, 64));
    }
    if (lane == 0) { ired[wid] = cmn; ired[8 + wid] = cmx; }
    __syncthreads();
    {
        int a0 = min(min(ired[0], ired[1]), min(ired[2], ired[3]));
        int a1 = min(min(ired[4], ired[5]), min(ired[6], ired[7]));
        cmn = min(a0, a1);
        int b0 = max(max(ired[8], ired[9]),  max(ired[10], ired[11]));
        int b1 = max(max(ired[12], ired[13]), max(ired[14], ired[15]));
        cmx = max(b0, b1);
    }

    // ---- level median c* via integer bisection (no histogram, no atomics) ----
    // c* = smallest c with W(<= c) >= 0.5, W = sum of deltas at levels <= c.
    // Invariant: W(<= lo) < 0.5 <= W(<= hi).
    int lo_c = cmn - 1, hi_c = cmx;
    int it = 0;
    #pragma unroll 1
    while (hi_c - lo_c > 1) {
        const int mid = (lo_c + hi_c) >> 1;   // uniform across block
        const int thr = mid - c_init;
        float s_loc = 0.0f;
        #pragma unroll
        for (int s = 0; s < VPT; ++s) {
            int off = (int)(c8[s >> 2] << ((3 - (s & 3)) * 8)) >> 24;  // sign-extended byte
            s_loc += (off <= thr) ? v[s] : 0.0f;
        }
        #pragma unroll
        for (int o = 32; o >= 1; o >>= 1) s_loc += __shfl_down(s_loc, o, 64);
        if (lane == 0) red[it * 8 + wid] = s_loc;
        __syncthreads();
        float S = 0.0f;
        #pragma unroll
        for (int w = 0; w < 8; ++w) S += red[it * 8 + w];
        if (S >= 0.5f) hi_c = mid; else lo_c = mid;
        ++it;
    }
    const int cstar = hi_c;

    // ---- w1 = (1/4096) * sum delta * |c - c*| (register pass + one reduction) ----
    float part = 0.0f;
    {
        const int thr = cstar - c_init;
        #pragma unroll
        for (int s = 0; s < VPT; ++s) {
            int off = (int)(c8[s >> 2] << ((3 - (s & 3)) * 8)) >> 24;
            part += v[s] * fabsf((float)(off - thr));
        }
    }
    #pragma unroll
    for (int o = 32; o >= 1; o >>= 1) part += __shfl_down(part, o, 64);
    if (lane == 0) red[15 * 8 + wid] = part;
    __syncthreads();
    if (tid == 0) {
        float w1 = 0.0f;
        #pragma unroll
        for (int w = 0; w < 8; ++w) w1 += red[15 * 8 + w];
        w1 *= (1.0f / 4096.0f);
        atomicAdd(out, w1 * (1.0f / (float)NPROJ));
    }
}

extern "C" void kernel_launch(void* const* d_in, const int* in_sizes, int n_in,
                              void* d_out, int out_size, void* d_ws, size_t ws_size,
                              hipStream_t stream) {
    const float* Xs = (const float*)d_in[0];
    const float* Xt = (const float*)d_in[1];
    const float* Us = (const float*)d_in[2];
    float* out = (float*)d_out;

    hipMemsetAsync(out, 0, sizeof(float), stream);
    swd_kernel<<<NPROJ, NB, 0, stream>>>(Xs, Xt, Us, out);
}